// Round 1
// baseline (200007.800 us; speedup 1.0000x reference)
//
#include <hip/hip_runtime.h>
#include <hip/hip_bf16.h>

// ---------------- types ----------------
typedef _Float16 half2_t __attribute__((ext_vector_type(2)));
typedef _Float16 half8_t __attribute__((ext_vector_type(8)));
typedef float float4_t __attribute__((ext_vector_type(4)));

#define SEQ   8192
#define ISZ   512
#define HID   2048
#define G4H   8192   // 4*HID
#define NB    256    // persistent blocks (== CU count)

#if __has_builtin(__builtin_amdgcn_fdot2)
#define DOT2(a, b, c) __builtin_amdgcn_fdot2((a), (b), (c), false)
#else
static __device__ __forceinline__ float DOT2(half2_t a, half2_t b, float c) {
    return c + (float)a.x * (float)b.x + (float)a.y * (float)b.y;
}
#endif

// ---------------- f32 -> f16 convert ----------------
__global__ __launch_bounds__(256) void cvt_f32_f16(const float* __restrict__ in,
                                                   _Float16* __restrict__ out, int n) {
    int i = (blockIdx.x * 256 + threadIdx.x) * 4;
    if (i < n) {
        float4 v = *(const float4*)(in + i);
        out[i + 0] = (_Float16)v.x;
        out[i + 1] = (_Float16)v.y;
        out[i + 2] = (_Float16)v.z;
        out[i + 3] = (_Float16)v.w;
    }
}

// ---------------- init h buffer + flags ----------------
__global__ __launch_bounds__(256) void init_state(_Float16* __restrict__ hbuf,
                                                  unsigned* __restrict__ flags) {
    int i = blockIdx.x * 256 + threadIdx.x;
    if (i < 2 * HID) ((unsigned short*)hbuf)[i] = 0;  // h[0] = h[1] = 0
    if (i < NB * 16) flags[i] = 0;
}

// ---------------- x_proj GEMM: C[m][n] = sum_k A[m][k]*B[n][k] (f16 in, f16 out, f32 acc)
__global__ __launch_bounds__(256) void gemm_xproj(const _Float16* __restrict__ A,  // [SEQ][ISZ]
                                                  const _Float16* __restrict__ B,  // [G4H][ISZ]
                                                  _Float16* __restrict__ C) {      // [SEQ][G4H]
    __shared__ _Float16 As[128 * 40];  // pitch 40 halves = 80 B (16B-aligned, conflict-swizzled)
    __shared__ _Float16 Bs[128 * 40];
    const int tid = threadIdx.x;
    const int bm = blockIdx.y, bn = blockIdx.x;
    const int wave = tid >> 6, lane = tid & 63;
    const int wr = wave >> 1, wc = wave & 1;
    const int l15 = lane & 15, lq = lane >> 4;

    float4_t acc[4][4];
#pragma unroll
    for (int im = 0; im < 4; im++)
#pragma unroll
        for (int in = 0; in < 4; in++)
#pragma unroll
            for (int r = 0; r < 4; r++) acc[im][in][r] = 0.f;

    for (int kt = 0; kt < ISZ; kt += 32) {
        __syncthreads();
#pragma unroll
        for (int ld = 0; ld < 2; ld++) {
            int c = tid + ld * 256;        // 0..511 chunk id (16B chunks)
            int r = c >> 2, ko = (c & 3) * 8;
            uint4 av = *(const uint4*)(A + (size_t)(bm * 128 + r) * ISZ + kt + ko);
            *(uint4*)(As + r * 40 + ko) = av;
            uint4 bv = *(const uint4*)(B + (size_t)(bn * 128 + r) * ISZ + kt + ko);
            *(uint4*)(Bs + r * 40 + ko) = bv;
        }
        __syncthreads();
        half8_t af[4], bf[4];
#pragma unroll
        for (int im = 0; im < 4; im++)
            af[im] = *(half8_t*)(As + (wr * 64 + im * 16 + l15) * 40 + lq * 8);
#pragma unroll
        for (int in = 0; in < 4; in++)
            bf[in] = *(half8_t*)(Bs + (wc * 64 + in * 16 + l15) * 40 + lq * 8);
#pragma unroll
        for (int im = 0; im < 4; im++)
#pragma unroll
            for (int in = 0; in < 4; in++)
                acc[im][in] = __builtin_amdgcn_mfma_f32_16x16x32_f16(af[im], bf[in], acc[im][in], 0, 0, 0);
    }
#pragma unroll
    for (int im = 0; im < 4; im++) {
        int mg = bm * 128 + wr * 64 + im * 16 + lq * 4;
#pragma unroll
        for (int in = 0; in < 4; in++) {
            int ng = bn * 128 + wc * 64 + in * 16 + l15;
#pragma unroll
            for (int r = 0; r < 4; r++)
                C[(size_t)(mg + r) * G4H + ng] = (_Float16)acc[im][in][r];
        }
    }
}

// ---------------- persistent LSTM recurrence ----------------
// Block b owns h elements [b*8, b*8+8) and rows {g*2048 + b*8 + e : g in 0..3, e in 0..7}.
// Wave g computes gate g. Weights live in VGPRs (f16), h broadcast via global + flags.
__global__ __launch_bounds__(256, 1) void lstm_persist(
    const float* __restrict__ Whh,   // [G4H][HID] f32
    const float* __restrict__ b_ih, const float* __restrict__ b_hh,
    const _Float16* __restrict__ xp, // [SEQ][G4H] f16
    const float* __restrict__ fcw, const float* __restrict__ fcb,
    _Float16* __restrict__ hbuf,     // [2][HID] f16
    unsigned* __restrict__ flags,    // [NB*16] u32 (64B stride)
    float* __restrict__ out) {
    const int b = blockIdx.x, tid = threadIdx.x;
    const int g = tid >> 6, lane = tid & 63;

    __shared__ float gate_lds[4][8];
    __shared__ unsigned short h16[8];
    __shared__ float red[4];

    // --- prologue: load this thread's weight slice into registers (f32 -> f16) ---
    half2_t w[8][16];  // 8 rows (e) x 32 cols (ct*32 ..) -> 128 VGPRs
#pragma unroll
    for (int e = 0; e < 8; e++) {
        const float* wp = Whh + (size_t)(g * HID + b * 8 + e) * HID + lane * 32;
#pragma unroll
        for (int i = 0; i < 16; i++) {
            float2 f = *(const float2*)(wp + i * 2);
            half2_t h2;
            h2.x = (_Float16)f.x;
            h2.y = (_Float16)f.y;
            w[e][i] = h2;
        }
    }
    float bias_r = 0.f;
    if (lane < 8) {
        int R = g * HID + b * 8 + lane;
        bias_r = b_ih[R] + b_hh[R];
    }
    float c_reg = 0.f;  // cell state, held by tid<8

    for (int t = 0; t < SEQ; ++t) {
        // x_proj prefetch (independent of h)
        float xpv = 0.f;
        if (lane < 8)
            xpv = (float)xp[(size_t)t * G4H + g * HID + b * 8 + lane];

        // wait until h[t] available from all blocks
        bool ok;
        do {
            unsigned f = __hip_atomic_load(&flags[tid * 16], __ATOMIC_RELAXED,
                                           __HIP_MEMORY_SCOPE_AGENT);
            ok = (f >= (unsigned)t);
        } while (!__syncthreads_and((int)ok));
        __threadfence();  // acquire: invalidate stale cached h

        // load h slice [lane*32, lane*32+32) into registers
        const uint4* hp = (const uint4*)(hbuf + (size_t)(t & 1) * HID);
        union {
            uint4 u[4];
            half2_t h2[16];
        } hu;
#pragma unroll
        for (int i = 0; i < 4; i++) hu.u[i] = hp[lane * 4 + i];

        // matvec: 8 rows x 32 cols per thread
        float acc[8];
#pragma unroll
        for (int e = 0; e < 8; e++) {
            float a = 0.f;
#pragma unroll
            for (int i = 0; i < 16; i++) a = DOT2(w[e][i], hu.h2[i], a);
            acc[e] = a;
        }
        // full-wave butterfly reduce (all 8 rows)
#pragma unroll
        for (int off = 1; off < 64; off <<= 1)
#pragma unroll
            for (int e = 0; e < 8; e++) acc[e] += __shfl_xor(acc[e], off, 64);

        if (lane < 8) {
            float v = acc[0];
#pragma unroll
            for (int e = 1; e < 8; e++)
                if (lane == e) v = acc[e];
            gate_lds[g][lane] = v + bias_r + xpv;
        }
        __syncthreads();

        if (tid < 8) {
            float gi = gate_lds[0][tid], gf = gate_lds[1][tid];
            float gg = gate_lds[2][tid], go = gate_lds[3][tid];
            float si = 1.f / (1.f + __expf(-gi));
            float sf = 1.f / (1.f + __expf(-gf));
            float so = 1.f / (1.f + __expf(-go));
            float tg = tanhf(gg);
            c_reg = sf * c_reg + si * tg;
            float h = so * tanhf(c_reg);
            _Float16 hh = (_Float16)h;
            h16[tid] = *(unsigned short*)&hh;
        }
        __syncthreads();

        if (tid == 0) {
            uint4 hv = *(const uint4*)h16;
            *(uint4*)(hbuf + (size_t)((t + 1) & 1) * HID + b * 8) = hv;
            __threadfence();  // release: drain + write back before flag
            __hip_atomic_store(&flags[b * 16], (unsigned)(t + 1), __ATOMIC_RELEASE,
                               __HIP_MEMORY_SCOPE_AGENT);
        }
    }

    // --- final fc on h_SEQ (parity 0) by block 0 ---
    if (b == 0) {
        bool ok;
        do {
            unsigned f = __hip_atomic_load(&flags[tid * 16], __ATOMIC_RELAXED,
                                           __HIP_MEMORY_SCOPE_AGENT);
            ok = (f >= (unsigned)SEQ);
        } while (!__syncthreads_and((int)ok));
        __threadfence();
        float s = 0.f;
#pragma unroll
        for (int i = 0; i < 8; i++) {
            float hv = (float)hbuf[(SEQ & 1) * HID + tid * 8 + i];
            s += hv * fcw[tid * 8 + i];
        }
#pragma unroll
        for (int off = 1; off < 64; off <<= 1) s += __shfl_xor(s, off, 64);
        if (lane == 0) red[g] = s;
        __syncthreads();
        if (tid == 0) out[0] = red[0] + red[1] + red[2] + red[3] + fcb[0];
    }
}

// ---------------- launch ----------------
extern "C" void kernel_launch(void* const* d_in, const int* in_sizes, int n_in,
                              void* d_out, int out_size, void* d_ws, size_t ws_size,
                              hipStream_t stream) {
    const float* input = (const float*)d_in[0];  // [SEQ][ISZ]
    const float* W_ih = (const float*)d_in[1];   // [G4H][ISZ]
    const float* W_hh = (const float*)d_in[2];   // [G4H][HID]
    const float* b_ih = (const float*)d_in[3];
    const float* b_hh = (const float*)d_in[4];
    const float* fc_w = (const float*)d_in[5];
    const float* fc_b = (const float*)d_in[6];
    float* out = (float*)d_out;

    char* ws = (char*)d_ws;
    _Float16* xp16 = (_Float16*)ws;                        // 134,217,728 B
    _Float16* A16 = (_Float16*)(ws + 134217728);           // 8,388,608 B
    _Float16* B16 = (_Float16*)(ws + 142606336);           // 8,388,608 B
    _Float16* hbuf = (_Float16*)(ws + 150994944);          // 8,192 B
    unsigned* flags = (unsigned*)(ws + 151003136);         // 16,384 B

    cvt_f32_f16<<<(SEQ * ISZ) / 1024, 256, 0, stream>>>(input, A16, SEQ * ISZ);
    cvt_f32_f16<<<(G4H * ISZ) / 1024, 256, 0, stream>>>(W_ih, B16, G4H * ISZ);
    init_state<<<16, 256, 0, stream>>>(hbuf, flags);

    dim3 gg(G4H / 128, SEQ / 128);
    gemm_xproj<<<gg, 256, 0, stream>>>(A16, B16, xp16);

    lstm_persist<<<NB, 256, 0, stream>>>(W_hh, b_ih, b_hh, xp16, fc_w, fc_b,
                                         hbuf, flags, out);
}